// Round 16
// baseline (257.652 us; speedup 1.0000x reference)
//
#include <hip/hip_runtime.h>
#include <math.h>

typedef __attribute__((ext_vector_type(8))) short short8;
typedef __attribute__((ext_vector_type(4))) float f32x4;
typedef __attribute__((ext_vector_type(2))) float f32x2;
typedef __attribute__((ext_vector_type(2))) unsigned int uint2v;

#define DEV __device__ __forceinline__

static constexpr int B_ = 4, C_ = 256, S_ = 2048, H_ = 8, O3_ = 768;
static constexpr int TOPK = 512;
static constexpr int QT = 16;           // q rows per workgroup in attention
static constexpr int QCOLS = 512;       // score cols per quarter pass
static constexpr int QSTR = 516;        // fp32 score row stride (quarter buffer)
static constexpr int QBUF = 16 * QSTR;  // floats per quarter buffer (8256)
static constexpr int PSTH = 1024;       // bf16 P half row stride
static constexpr int P1OFF = 2 * QBUF;  // ushort offset of P1 (64-aligned -> swizzle bijective)
static constexpr size_t K3_LDS_BYTES = (size_t)2 * QBUF * 4;  // 66048 B -> 2 WGs/CU

// k_qkvf geometry
static constexpr int XQSTR = 40;        // staging row stride (ushorts)
static constexpr int NROWS = 80;        // staged s-rows (padded; [0,66) valid)
static constexpr int RSTR = 85;         // relay row stride (floats)

DEV unsigned cvt_pk_bf16(float a, float b) {
  unsigned r;
  asm("v_cvt_pk_bf16_f32 %0, %1, %2" : "=v"(r) : "v"(a), "v"(b));
  return r;  // lo16 = bf16(a), hi16 = bf16(b)
}
DEV unsigned short f2bf1(float f) { return (unsigned short)(cvt_pk_bf16(f, f) & 0xFFFFu); }
DEV void hilo(float f, unsigned short& h, unsigned short& l) {
  unsigned p = cvt_pk_bf16(f, f);
  h = (unsigned short)p;
  float r = f - __uint_as_float(p << 16);
  l = (unsigned short)(cvt_pk_bf16(r, r) & 0xFFFFu);
}

// ---------------- K0a: weights -> bf16 hi/lo (qkv), bf16 (proj) ----------------
__global__ void k_convw(const float* __restrict__ wqkv, const float* __restrict__ wproj,
                        unsigned short* __restrict__ wq_hi, unsigned short* __restrict__ wq_lo,
                        unsigned short* __restrict__ wproj_bf) {
  int i = blockIdx.x * 256 + threadIdx.x;
  if (i < O3_ * C_) {
    unsigned short h, l;
    hilo(wqkv[i], h, l);
    wq_hi[i] = h;
    wq_lo[i] = l;
  }
  if (i < C_ * C_) wproj_bf[i] = f2bf1(wproj[i]);
}

// ---------------- K1: fused qkv GEMM + depthwise conv + l2norm + hilo split ----------------
__global__ __launch_bounds__(512) void k_qkvf(const unsigned short* __restrict__ w_hi,
                                              const unsigned short* __restrict__ w_lo,
                                              const float* __restrict__ x,
                                              const float* __restrict__ wdw,
                                              const float* __restrict__ temp,
                                              unsigned short* __restrict__ q_hi,
                                              unsigned short* __restrict__ q_lo,
                                              unsigned short* __restrict__ k_hi,
                                              unsigned short* __restrict__ k_lo,
                                              unsigned short* __restrict__ vt) {
  __shared__ unsigned short xh[2][NROWS * XQSTR];
  __shared__ unsigned short xl[2][NROWS * XQSTR];
  __shared__ float raw[96 * RSTR];
  int n0 = blockIdx.x * 64;
  int h = blockIdx.y;
  int b = blockIdx.z;
  int tid = threadIdx.x, lane = tid & 63, wv = tid >> 6;
  int l15 = lane & 15, lh = lane >> 4;
  const float* xb = x + (size_t)b * C_ * S_;

  int kc = tid >> 4;
  int sg = tid & 15;
  auto stage = [&](int ks, int bufi) {
    int k0 = ks * 32;
    const float* xc = xb + (size_t)(k0 + kc) * S_ + n0 - 1;
#pragma unroll
    for (int j = 0; j < 5; ++j) {
      int sr = sg + 16 * j;
      if (sr < 66) {
        int s = n0 - 1 + sr;
        float f = (s >= 0 && s < S_) ? xc[sr] : 0.f;
        unsigned short hh, ll;
        hilo(f, hh, ll);
        xh[bufi][sr * XQSTR + kc] = hh;
        xl[bufi][sr * XQSTR + kc] = ll;
      }
    }
  };

  int mt = wv;
  int obase = (mt >> 1) * 256 + h * 32 + (mt & 1) * 16;
  f32x4 acc[5] = {};

  stage(0, 0);
  for (int ks = 0; ks < 8; ++ks) {
    __syncthreads();
    if (ks < 7) stage(ks + 1, (ks + 1) & 1);
    if (wv < 6) {
      int kk = lh * 8;
      short8 ahf = *(const short8*)(w_hi + (size_t)(obase + l15) * C_ + ks * 32 + kk);
      short8 alf = *(const short8*)(w_lo + (size_t)(obase + l15) * C_ + ks * 32 + kk);
#pragma unroll
      for (int n = 0; n < 5; ++n) {
        const unsigned short* bh_ = &xh[ks & 1][(n * 16 + l15) * XQSTR + kk];
        const unsigned short* bl_ = &xl[ks & 1][(n * 16 + l15) * XQSTR + kk];
        short8 bh = *(const short8*)bh_;
        short8 bl = *(const short8*)bl_;
        acc[n] = __builtin_amdgcn_mfma_f32_16x16x32_bf16(ahf, bh, acc[n], 0, 0, 0);
        acc[n] = __builtin_amdgcn_mfma_f32_16x16x32_bf16(ahf, bl, acc[n], 0, 0, 0);
        acc[n] = __builtin_amdgcn_mfma_f32_16x16x32_bf16(alf, bh, acc[n], 0, 0, 0);
      }
    }
  }
  __syncthreads();
  if (wv < 6) {
#pragma unroll
    for (int n = 0; n < 5; ++n)
#pragma unroll
      for (int r = 0; r < 4; ++r)
        raw[(mt * 16 + lh * 4 + r) * RSTR + n * 16 + l15] = acc[n][r];
  }
  __syncthreads();

  {
    int s_loc = tid >> 3;
    int dg = tid & 7;
    int s = n0 + s_loc;
    float tph = temp[h];
    size_t bh_ = (size_t)(b * H_ + h);
    float qv[4], kv[4], vv[4];
    float sq = 0.f, sk = 0.f;
#pragma unroll
    for (int dd = 0; dd < 4; ++dd) {
      int d = dg * 4 + dd;
      int oq = h * 32 + d;
      const float* wq = wdw + oq * 3;
      const float* wk = wdw + (oq + 256) * 3;
      const float* wvv = wdw + (oq + 512) * 3;
      const float* rq = &raw[d * RSTR + s_loc];
      const float* rk = &raw[(32 + d) * RSTR + s_loc];
      const float* rv = &raw[(64 + d) * RSTR + s_loc];
      float q = wq[0] * rq[0] + wq[1] * rq[1] + wq[2] * rq[2];
      float k = wk[0] * rk[0] + wk[1] * rk[1] + wk[2] * rk[2];
      float v = wvv[0] * rv[0] + wvv[1] * rv[1] + wvv[2] * rv[2];
      qv[dd] = q; sq += q * q;
      kv[dd] = k; sk += k * k;
      vv[dd] = v;
    }
#pragma unroll
    for (int m = 1; m < 8; m <<= 1) {
      sq += __shfl_xor(sq, m);
      sk += __shfl_xor(sk, m);
    }
    float iq = tph / fmaxf(sqrtf(sq), 1e-12f);
    float ik = 1.f / fmaxf(sqrtf(sk), 1e-12f);
    size_t base = (bh_ * S_ + s) * 32 + dg * 4;

    float q0 = qv[0] * iq, q1 = qv[1] * iq, q2 = qv[2] * iq, q3 = qv[3] * iq;
    unsigned qh01 = cvt_pk_bf16(q0, q1), qh23 = cvt_pk_bf16(q2, q3);
    *(uint2v*)(q_hi + base) = uint2v{qh01, qh23};
    float ql0 = q0 - __uint_as_float(qh01 << 16);
    float ql1 = q1 - __uint_as_float(qh01 & 0xFFFF0000u);
    float ql2 = q2 - __uint_as_float(qh23 << 16);
    float ql3 = q3 - __uint_as_float(qh23 & 0xFFFF0000u);
    *(uint2v*)(q_lo + base) = uint2v{cvt_pk_bf16(ql0, ql1), cvt_pk_bf16(ql2, ql3)};

    float k0 = kv[0] * ik, k1 = kv[1] * ik, k2 = kv[2] * ik, k3 = kv[3] * ik;
    unsigned kh01 = cvt_pk_bf16(k0, k1), kh23 = cvt_pk_bf16(k2, k3);
    *(uint2v*)(k_hi + base) = uint2v{kh01, kh23};
    float kl0 = k0 - __uint_as_float(kh01 << 16);
    float kl1 = k1 - __uint_as_float(kh01 & 0xFFFF0000u);
    float kl2 = k2 - __uint_as_float(kh23 << 16);
    float kl3 = k3 - __uint_as_float(kh23 & 0xFFFF0000u);
    *(uint2v*)(k_lo + base) = uint2v{cvt_pk_bf16(kl0, kl1), cvt_pk_bf16(kl2, kl3)};

#pragma unroll
    for (int dd = 0; dd < 4; ++dd) {
      int d = dg * 4 + dd;
      vt[(bh_ * 32 + d) * S_ + s] = f2bf1(vv[dd]);
    }
  }
}

// ---------------- K3: fused QK^T -> exact top-512 -> softmax -> PV ----------------
// R16: batched 3-pivot opening round (parallel compare streams) -> tight bracket -> Illinois.
__global__ __launch_bounds__(1024, 8) void k_attn(const unsigned short* __restrict__ q_hi,
                                                  const unsigned short* __restrict__ q_lo,
                                                  const unsigned short* __restrict__ k_hi,
                                                  const unsigned short* __restrict__ k_lo,
                                                  const unsigned short* __restrict__ vt,
                                                  unsigned short* __restrict__ ao) {
  extern __shared__ float smem[];
  __shared__ float is_arr[QT];
  unsigned short* Pb = (unsigned short*)smem;
  float* red = smem;
  int bid = blockIdx.x;
  int tile = bid & 127;
  int bh = bid >> 7;
  int q0 = tile * QT;
  int tid = threadIdx.x, lane = tid & 63, wv = tid >> 6;
  int l15 = lane & 15, lh = lane >> 4;
  const unsigned short* vb = vt + (size_t)bh * 32 * S_;

  size_t qoff = ((size_t)bh * S_ + q0 + l15) * 32 + lh * 8;
  short8 ah = *(const short8*)(q_hi + qoff);
  short8 al = *(const short8*)(q_lo + qoff);
  size_t kbase = (size_t)bh * S_ * 32;

  float v[32];

  short8 kh0, kl0, kh1, kl1;
  {
    const unsigned short* kp = k_hi + kbase + (size_t)(wv * 32 + l15) * 32 + lh * 8;
    const unsigned short* lp = k_lo + kbase + (size_t)(wv * 32 + l15) * 32 + lh * 8;
    kh0 = *(const short8*)(kp);       kl0 = *(const short8*)(lp);
    kh1 = *(const short8*)(kp + 512); kl1 = *(const short8*)(lp + 512);
  }
#pragma unroll
  for (int qq = 0; qq < 4; ++qq) {
    float* buf = smem + (qq & 1) * QBUF;
    {
      f32x4 d0 = {}, d1 = {};
      __builtin_amdgcn_s_setprio(1);
      d0 = __builtin_amdgcn_mfma_f32_16x16x32_bf16(ah, kh0, d0, 0, 0, 0);
      d0 = __builtin_amdgcn_mfma_f32_16x16x32_bf16(ah, kl0, d0, 0, 0, 0);
      d0 = __builtin_amdgcn_mfma_f32_16x16x32_bf16(al, kh0, d0, 0, 0, 0);
      d1 = __builtin_amdgcn_mfma_f32_16x16x32_bf16(ah, kh1, d1, 0, 0, 0);
      d1 = __builtin_amdgcn_mfma_f32_16x16x32_bf16(ah, kl1, d1, 0, 0, 0);
      d1 = __builtin_amdgcn_mfma_f32_16x16x32_bf16(al, kh1, d1, 0, 0, 0);
      __builtin_amdgcn_s_setprio(0);
      int tloc = wv * 32 + l15;
#pragma unroll
      for (int r = 0; r < 4; ++r) {
        buf[(lh * 4 + r) * QSTR + tloc] = d0[r];
        buf[(lh * 4 + r) * QSTR + tloc + 16] = d1[r];
      }
      if (qq < 3) {
        int colg = (qq + 1) * QCOLS + wv * 32;
        const unsigned short* kp = k_hi + kbase + (size_t)(colg + l15) * 32 + lh * 8;
        const unsigned short* lp = k_lo + kbase + (size_t)(colg + l15) * 32 + lh * 8;
        kh0 = *(const short8*)(kp);       kl0 = *(const short8*)(lp);
        kh1 = *(const short8*)(kp + 512); kl1 = *(const short8*)(lp + 512);
      }
    }
    __syncthreads();
#pragma unroll
    for (int kk2 = 0; kk2 < 4; ++kk2) {
      f32x2 pr = *(const f32x2*)&buf[wv * QSTR + kk2 * 128 + 2 * lane];
      v[qq * 8 + kk2 * 2] = pr[0];
      v[qq * 8 + kk2 * 2 + 1] = pr[1];
    }
  }

  // ---- selection (exact top-512) + softmax weights, in registers ----
  {
    float vmax = v[0], vmin = v[0], sum = 0.f, sqs = 0.f;
#pragma unroll
    for (int j = 0; j < 32; ++j) {
      vmax = fmaxf(vmax, v[j]); vmin = fminf(vmin, v[j]);
      sum += v[j]; sqs = fmaf(v[j], v[j], sqs);
    }
#pragma unroll
    for (int m = 1; m < 64; m <<= 1) {
      vmax = fmaxf(vmax, __shfl_xor(vmax, m));
      vmin = fminf(vmin, __shfl_xor(vmin, m));
      sum += __shfl_xor(sum, m);
      sqs += __shfl_xor(sqs, m);
    }
    float mu = sum * (1.f / 2048.f);
    float sig = sqrtf(fmaxf(sqs * (1.f / 2048.f) - mu * mu, 0.f));

    // Batched opening round: 3 pivots evaluated in one fused pass (independent cmp streams).
    float pv1 = mu + 0.67449f * sig;
    float pv0 = pv1 - 0.12f * sig;
    float pv2 = pv1 + 0.12f * sig;
    int c0 = 0, c1 = 0, c2 = 0;
#pragma unroll
    for (int j = 0; j < 32; ++j) {
      c0 += (int)__popcll(__ballot(v[j] > pv0));
      c1 += (int)__popcll(__ballot(v[j] > pv1));
      c2 += (int)__popcll(__ballot(v[j] > pv2));
    }
    // monotone: c0 >= c1 >= c2. Establish Illinois bracket (count(>vlo) > K >= count(>vhi)).
    float vlo, vhi, flo, fhi;
    int chi;
    float T = 0.f;
    bool exact = false;
    if (c0 == TOPK) { T = pv0; exact = true; chi = c0; vlo = vhi = pv0; flo = fhi = 0.f; }
    else if (c1 == TOPK) { T = pv1; exact = true; chi = c1; vlo = vhi = pv1; flo = fhi = 0.f; }
    else if (c2 == TOPK) { T = pv2; exact = true; chi = c2; vlo = vhi = pv2; flo = fhi = 0.f; }
    else if (c0 < TOPK) {  // threshold below pv0
      vlo = vmin - 1e-3f; flo = (float)(2048 - TOPK);
      vhi = pv0; fhi = (float)(c0 - TOPK); chi = c0;
    } else if (c1 > TOPK) {
      if (c2 > TOPK) {     // threshold above pv2
        vlo = pv2; flo = (float)(c2 - TOPK);
        vhi = vmax; fhi = (float)(0 - TOPK); chi = 0;
      } else {             // between pv1 and pv2
        vlo = pv1; flo = (float)(c1 - TOPK);
        vhi = pv2; fhi = (float)(c2 - TOPK); chi = c2;
      }
    } else {               // c0 > TOPK >= c1: between pv0 and pv1
      vlo = pv0; flo = (float)(c0 - TOPK);
      vhi = pv1; fhi = (float)(c1 - TOPK); chi = c1;
    }
    if (!exact) {
      int lastside = 0;
      for (int it = 0; it < 32; ++it) {
        float piv = vhi - fhi * (vhi - vlo) / (fhi - flo);
        if (!(piv > vlo && piv < vhi)) piv = 0.5f * (vlo + vhi);
        if (!(piv > vlo && piv < vhi)) break;  // interval collapsed (ties)
        int c = 0;
#pragma unroll
        for (int j = 0; j < 32; ++j)
          c += (int)__popcll(__ballot(v[j] > piv));
        if (c == TOPK) { T = piv; exact = true; break; }
        if (c > TOPK) {
          if (lastside == 1) fhi *= 0.5f;
          vlo = piv; flo = (float)(c - TOPK); lastside = 1;
        } else {
          if (lastside == -1) flo *= 0.5f;
          vhi = piv; fhi = (float)(c - TOPK); chi = c; lastside = -1;
        }
      }
    }
    int cntGT = exact ? TOPK : chi;
    if (!exact) T = vhi;

    unsigned selbits = 0;
#pragma unroll
    for (int j = 0; j < 32; ++j)
      if (v[j] > T) selbits |= (1u << j);
    int need = TOPK - cntGT;
    if (need > 0) {
      // ties by lowest col (jax order). col order: (k, lane, parity) ascending.
      int base = 0;
      unsigned long long lmask = (lane == 0) ? 0ull : (~0ull >> (64 - lane));
#pragma unroll
      for (int k = 0; k < 16; ++k) {
        bool t0 = (v[2 * k] == T), t1 = (v[2 * k + 1] == T);
        unsigned long long m0 = __ballot(t0);
        unsigned long long m1 = __ballot(t1);
        int before = base + (int)__popcll(m0 & lmask) + (int)__popcll(m1 & lmask);
        int r0 = before;
        int r1 = before + (t0 ? 1 : 0);
        if (t0 && r0 < need) selbits |= (1u << (2 * k));
        if (t1 && r1 < need) selbits |= (1u << (2 * k + 1));
        base += (int)__popcll(m0) + (int)__popcll(m1);
      }
    }

    float ssum = 0.f;
#pragma unroll
    for (int j = 0; j < 32; ++j) {
      float e = ((selbits >> j) & 1u) ? __expf(v[j] - vmax) : 0.f;
      v[j] = e;
      ssum += e;
    }
#pragma unroll
    for (int m = 1; m < 64; m <<= 1) ssum += __shfl_xor(ssum, m);
    if (lane == 0) is_arr[wv] = 1.f / ssum;
  }

  f32x4 acc0 = {}, acc1 = {};
  int swz_w = (wv & 7) << 3;
  int swz_r = (l15 & 7) << 3;
#pragma unroll
  for (int kk = 0; kk < 8; ++kk) {
    int lc = (kk >> 2) * 512 + (kk & 3) * 128 + 2 * lane;
    unsigned pk = cvt_pk_bf16(v[2 * kk], v[2 * kk + 1]);
    *(unsigned*)&Pb[(wv * PSTH + lc) ^ swz_w] = pk;
  }
  __syncthreads();
  {
#pragma unroll
    for (int kk = 0; kk < 8; ++kk) {
      int lc = (kk >> 2) * 512 + (kk & 3) * 128 + 2 * lane;
      unsigned pk = cvt_pk_bf16(v[16 + 2 * kk], v[16 + 2 * kk + 1]);
      *(unsigned*)&Pb[P1OFF + ((wv * PSTH + lc) ^ swz_w)] = pk;
    }
    const unsigned short* v0p = vb + (size_t)l15 * S_ + wv * 64 + lh * 8;
    const unsigned short* v1p = v0p + 16 * S_;
#pragma unroll
    for (int kt = 0; kt < 2; ++kt) {
      int lc = wv * 64 + kt * 32 + lh * 8;
      short8 a = *(const short8*)(Pb + ((l15 * PSTH + lc) ^ swz_r));
      short8 b0 = *(const short8*)(v0p + kt * 32);
      short8 b1 = *(const short8*)(v1p + kt * 32);
      __builtin_amdgcn_s_setprio(1);
      acc0 = __builtin_amdgcn_mfma_f32_16x16x32_bf16(a, b0, acc0, 0, 0, 0);
      acc1 = __builtin_amdgcn_mfma_f32_16x16x32_bf16(a, b1, acc1, 0, 0, 0);
      __builtin_amdgcn_s_setprio(0);
    }
  }
  __syncthreads();
  {
    const unsigned short* v0p = vb + (size_t)l15 * S_ + 1024 + wv * 64 + lh * 8;
    const unsigned short* v1p = v0p + 16 * S_;
#pragma unroll
    for (int kt = 0; kt < 2; ++kt) {
      int lc = wv * 64 + kt * 32 + lh * 8;
      short8 a = *(const short8*)(Pb + P1OFF + ((l15 * PSTH + lc) ^ swz_r));
      short8 b0 = *(const short8*)(v0p + kt * 32);
      short8 b1 = *(const short8*)(v1p + kt * 32);
      __builtin_amdgcn_s_setprio(1);
      acc0 = __builtin_amdgcn_mfma_f32_16x16x32_bf16(a, b0, acc0, 0, 0, 0);
      acc1 = __builtin_amdgcn_mfma_f32_16x16x32_bf16(a, b1, acc1, 0, 0, 0);
      __builtin_amdgcn_s_setprio(0);
    }
  }
  __syncthreads();

#pragma unroll
  for (int r = 0; r < 4; ++r) {
    red[wv * 529 + (lh * 4 + r) * 33 + l15] = acc0[r];
    red[wv * 529 + (lh * 4 + r) * 33 + 16 + l15] = acc1[r];
  }
  __syncthreads();
  if (tid < 512) {
    int row = tid >> 5, d = tid & 31;
    float s = 0.f;
#pragma unroll
    for (int w = 0; w < 16; ++w) s += red[w * 529 + row * 33 + d];
    s *= is_arr[row];
    ao[((size_t)bh * S_ + q0 + row) * 32 + d] = f2bf1(s);
  }
}

// ---------------- K4: output projection ----------------
__global__ __launch_bounds__(256) void k_proj(const unsigned short* __restrict__ wbf,
                                              const unsigned short* __restrict__ ao,
                                              float* __restrict__ out) {
  int b = blockIdx.z;
  int m0 = blockIdx.y * 64, n0 = blockIdx.x * 64;
  int tid = threadIdx.x, lane = tid & 63, wid = tid >> 6;
  int l15 = lane & 15, lh = lane >> 4;
  int wm = (wid >> 1) * 32, wn = (wid & 1) * 32;
  const unsigned short* aob = ao + (size_t)b * H_ * S_ * 32;
  f32x4 acc[2][2] = {};
  int mA = m0 + wm + l15;
  int nB = n0 + wn + l15;
  for (int k0 = 0; k0 < C_; k0 += 32) {
    int kk = k0 + lh * 8;
    int hh = kk >> 5;
    int dd = kk & 31;
    short8 a0 = *(const short8*)(wbf + (size_t)mA * C_ + kk);
    short8 a1 = *(const short8*)(wbf + (size_t)(mA + 16) * C_ + kk);
    short8 b0 = *(const short8*)(aob + ((size_t)hh * S_ + nB) * 32 + dd);
    short8 b1 = *(const short8*)(aob + ((size_t)hh * S_ + nB + 16) * 32 + dd);
    acc[0][0] = __builtin_amdgcn_mfma_f32_16x16x32_bf16(a0, b0, acc[0][0], 0, 0, 0);
    acc[0][1] = __builtin_amdgcn_mfma_f32_16x16x32_bf16(a0, b1, acc[0][1], 0, 0, 0);
    acc[1][0] = __builtin_amdgcn_mfma_f32_16x16x32_bf16(a1, b0, acc[1][0], 0, 0, 0);
    acc[1][1] = __builtin_amdgcn_mfma_f32_16x16x32_bf16(a1, b1, acc[1][1], 0, 0, 0);
  }
  float* ob = out + (size_t)b * C_ * S_;
#pragma unroll
  for (int i = 0; i < 2; ++i)
#pragma unroll
    for (int j = 0; j < 2; ++j)
#pragma unroll
      for (int r = 0; r < 4; ++r) {
        int row = m0 + wm + i * 16 + lh * 4 + r;
        int col = n0 + wn + j * 16 + l15;
        ob[(size_t)row * S_ + col] = acc[i][j][r];
      }
}

extern "C" void kernel_launch(void* const* d_in, const int* in_sizes, int n_in,
                              void* d_out, int out_size, void* d_ws, size_t ws_size,
                              hipStream_t stream) {
  const float* x = (const float*)d_in[0];
  const float* wqkv = (const float*)d_in[1];
  const float* wdw = (const float*)d_in[2];
  const float* wproj = (const float*)d_in[3];
  const float* temp = (const float*)d_in[4];
  float* out = (float*)d_out;

  char* ws = (char*)d_ws;
  size_t off = 0;
  auto alloc = [&](size_t bytes) -> void* {
    void* p = ws + off;
    off += (bytes + 255) & ~(size_t)255;
    return p;
  };
  unsigned short* wq_hi    = (unsigned short*)alloc((size_t)O3_ * C_ * 2);
  unsigned short* wq_lo    = (unsigned short*)alloc((size_t)O3_ * C_ * 2);
  unsigned short* wproj_bf = (unsigned short*)alloc((size_t)C_ * C_ * 2);
  unsigned short* q_hi     = (unsigned short*)alloc((size_t)B_ * H_ * S_ * 32 * 2);
  unsigned short* q_lo     = (unsigned short*)alloc((size_t)B_ * H_ * S_ * 32 * 2);
  unsigned short* k_hi     = (unsigned short*)alloc((size_t)B_ * H_ * S_ * 32 * 2);
  unsigned short* k_lo     = (unsigned short*)alloc((size_t)B_ * H_ * S_ * 32 * 2);
  unsigned short* vt       = (unsigned short*)alloc((size_t)B_ * H_ * 32 * S_ * 2);
  unsigned short* ao       = (unsigned short*)alloc((size_t)B_ * H_ * S_ * 32 * 2);

  (void)hipFuncSetAttribute(reinterpret_cast<const void*>(k_attn),
                            hipFuncAttributeMaxDynamicSharedMemorySize, (int)K3_LDS_BYTES);

  k_convw<<<dim3((O3_ * C_ + 255) / 256), dim3(256), 0, stream>>>(wqkv, wproj, wq_hi, wq_lo, wproj_bf);
  k_qkvf<<<dim3(S_ / 64, H_, B_), dim3(512), 0, stream>>>(wq_hi, wq_lo, x, wdw, temp,
                                                          q_hi, q_lo, k_hi, k_lo, vt);
  k_attn<<<dim3(B_ * H_ * (S_ / QT)), dim3(1024), K3_LDS_BYTES, stream>>>(q_hi, q_lo, k_hi, k_lo, vt, ao);
  k_proj<<<dim3(S_ / 64, C_ / 64, B_), dim3(256), 0, stream>>>(wproj_bf, ao, out);
}

// Round 17
// 240.537 us; speedup vs baseline: 1.0711x; 1.0711x over previous
//
#include <hip/hip_runtime.h>
#include <math.h>

typedef __attribute__((ext_vector_type(8))) short short8;
typedef __attribute__((ext_vector_type(4))) float f32x4;
typedef __attribute__((ext_vector_type(2))) float f32x2;
typedef __attribute__((ext_vector_type(2))) unsigned int uint2v;

#define DEV __device__ __forceinline__

static constexpr int B_ = 4, C_ = 256, S_ = 2048, H_ = 8, O3_ = 768;
static constexpr int TOPK = 512;
static constexpr int QT = 16;           // q rows per workgroup in attention
static constexpr int QCOLS = 512;       // score cols per quarter pass
static constexpr int QSTR = 516;        // fp32 score row stride (quarter buffer)
static constexpr int QBUF = 16 * QSTR;  // floats per quarter buffer (8256)
static constexpr int PSTH = 1024;       // bf16 P half row stride
static constexpr int P1OFF = 2 * QBUF;  // ushort offset of P1 (64-aligned -> swizzle bijective)
static constexpr size_t K3_LDS_BYTES = (size_t)2 * QBUF * 4;  // 66048 B -> 2 WGs/CU

// k_qkvf geometry
static constexpr int XQSTR = 40;        // staging row stride (ushorts); 80B, 16B-aligned, bank-spread
static constexpr int NROWS = 80;        // staged s-rows (padded; [0,66) valid)
static constexpr int RSTR = 85;         // relay row stride (floats)

DEV unsigned cvt_pk_bf16(float a, float b) {
  unsigned r;
  asm("v_cvt_pk_bf16_f32 %0, %1, %2" : "=v"(r) : "v"(a), "v"(b));
  return r;  // lo16 = bf16(a), hi16 = bf16(b)
}
DEV unsigned short f2bf1(float f) { return (unsigned short)(cvt_pk_bf16(f, f) & 0xFFFFu); }
DEV void hilo(float f, unsigned short& h, unsigned short& l) {
  unsigned p = cvt_pk_bf16(f, f);
  h = (unsigned short)p;
  float r = f - __uint_as_float(p << 16);
  l = (unsigned short)(cvt_pk_bf16(r, r) & 0xFFFFu);
}

// ---------------- K0a: weights -> bf16 hi/lo (qkv), bf16 (proj) ----------------
__global__ void k_convw(const float* __restrict__ wqkv, const float* __restrict__ wproj,
                        unsigned short* __restrict__ wq_hi, unsigned short* __restrict__ wq_lo,
                        unsigned short* __restrict__ wproj_bf) {
  int i = blockIdx.x * 256 + threadIdx.x;
  if (i < O3_ * C_) {
    unsigned short h, l;
    hilo(wqkv[i], h, l);
    wq_hi[i] = h;
    wq_lo[i] = l;
  }
  if (i < C_ * C_) wproj_bf[i] = f2bf1(wproj[i]);
}

// ---------------- K1: fused qkv GEMM + depthwise conv + l2norm + hilo split ----------------
// Grid (S/64, H, B), 512 thr (8 waves). Division-free staging: thread t owns channel t>>4;
// its 16-thread group covers 66 s-rows in 5 predicated steps.
__global__ __launch_bounds__(512) void k_qkvf(const unsigned short* __restrict__ w_hi,
                                              const unsigned short* __restrict__ w_lo,
                                              const float* __restrict__ x,
                                              const float* __restrict__ wdw,
                                              const float* __restrict__ temp,
                                              unsigned short* __restrict__ q_hi,
                                              unsigned short* __restrict__ q_lo,
                                              unsigned short* __restrict__ k_hi,
                                              unsigned short* __restrict__ k_lo,
                                              unsigned short* __restrict__ vt) {
  __shared__ unsigned short xh[2][NROWS * XQSTR];  // 2 x 6400 B
  __shared__ unsigned short xl[2][NROWS * XQSTR];
  __shared__ float raw[96 * RSTR];                 // 32640 B
  int n0 = blockIdx.x * 64;
  int h = blockIdx.y;
  int b = blockIdx.z;
  int tid = threadIdx.x, lane = tid & 63, wv = tid >> 6;
  int l15 = lane & 15, lh = lane >> 4;
  const float* xb = x + (size_t)b * C_ * S_;

  // staging roles (division-free): channel kc = tid>>4 (0..31), s-group base = tid&15
  int kc = tid >> 4;
  int sg = tid & 15;
  // stage K-step tile: c in [k0,k0+32), s-rows [0,66) = s in [n0-1, n0+65), zero at edges
  auto stage = [&](int ks, int bufi) {
    int k0 = ks * 32;
    const float* xc = xb + (size_t)(k0 + kc) * S_ + n0 - 1;
#pragma unroll
    for (int j = 0; j < 5; ++j) {
      int sr = sg + 16 * j;
      if (sr < 66) {
        int s = n0 - 1 + sr;
        float f = (s >= 0 && s < S_) ? xc[sr] : 0.f;
        unsigned short hh, ll;
        hilo(f, hh, ll);
        xh[bufi][sr * XQSTR + kc] = hh;
        xl[bufi][sr * XQSTR + kc] = ll;
      }
    }
  };

  // wave wv<6 owns M-tile wv: rows obase..obase+15
  int mt = wv;
  int obase = (mt >> 1) * 256 + h * 32 + (mt & 1) * 16;  // q/k/v channel block
  f32x4 acc[5] = {};

  stage(0, 0);
  for (int ks = 0; ks < 8; ++ks) {
    __syncthreads();  // buf ks&1 staged; prior buffer's reads fenced
    if (ks < 7) stage(ks + 1, (ks + 1) & 1);
    if (wv < 6) {
      int kk = lh * 8;
      short8 ahf = *(const short8*)(w_hi + (size_t)(obase + l15) * C_ + ks * 32 + kk);
      short8 alf = *(const short8*)(w_lo + (size_t)(obase + l15) * C_ + ks * 32 + kk);
#pragma unroll
      for (int n = 0; n < 5; ++n) {
        const unsigned short* bh_ = &xh[ks & 1][(n * 16 + l15) * XQSTR + kk];
        const unsigned short* bl_ = &xl[ks & 1][(n * 16 + l15) * XQSTR + kk];
        short8 bh = *(const short8*)bh_;
        short8 bl = *(const short8*)bl_;
        acc[n] = __builtin_amdgcn_mfma_f32_16x16x32_bf16(ahf, bh, acc[n], 0, 0, 0);
        acc[n] = __builtin_amdgcn_mfma_f32_16x16x32_bf16(ahf, bl, acc[n], 0, 0, 0);
        acc[n] = __builtin_amdgcn_mfma_f32_16x16x32_bf16(alf, bh, acc[n], 0, 0, 0);
      }
    }
  }
  __syncthreads();  // all MFMA reads of staging done
  if (wv < 6) {
#pragma unroll
    for (int n = 0; n < 5; ++n)
#pragma unroll
      for (int r = 0; r < 4; ++r)
        raw[(mt * 16 + lh * 4 + r) * RSTR + n * 16 + l15] = acc[n][r];
  }
  __syncthreads();  // raw tile complete

  // ---- epilogue: conv3 + l2norm + temperature + hilo stores ----
  {
    int s_loc = tid >> 3;   // 0..63
    int dg = tid & 7;       // d-group (4 d's)
    int s = n0 + s_loc;
    float tph = temp[h];
    size_t bh_ = (size_t)(b * H_ + h);
    float qv[4], kv[4], vv[4];
    float sq = 0.f, sk = 0.f;
#pragma unroll
    for (int dd = 0; dd < 4; ++dd) {
      int d = dg * 4 + dd;
      int oq = h * 32 + d;
      const float* wq = wdw + oq * 3;
      const float* wk = wdw + (oq + 256) * 3;
      const float* wvv = wdw + (oq + 512) * 3;
      const float* rq = &raw[d * RSTR + s_loc];
      const float* rk = &raw[(32 + d) * RSTR + s_loc];
      const float* rv = &raw[(64 + d) * RSTR + s_loc];
      float q = wq[0] * rq[0] + wq[1] * rq[1] + wq[2] * rq[2];
      float k = wk[0] * rk[0] + wk[1] * rk[1] + wk[2] * rk[2];
      float v = wvv[0] * rv[0] + wvv[1] * rv[1] + wvv[2] * rv[2];
      qv[dd] = q; sq += q * q;
      kv[dd] = k; sk += k * k;
      vv[dd] = v;
    }
#pragma unroll
    for (int m = 1; m < 8; m <<= 1) {
      sq += __shfl_xor(sq, m);
      sk += __shfl_xor(sk, m);
    }
    float iq = tph / fmaxf(sqrtf(sq), 1e-12f);
    float ik = 1.f / fmaxf(sqrtf(sk), 1e-12f);
    size_t base = (bh_ * S_ + s) * 32 + dg * 4;

    float q0 = qv[0] * iq, q1 = qv[1] * iq, q2 = qv[2] * iq, q3 = qv[3] * iq;
    unsigned qh01 = cvt_pk_bf16(q0, q1), qh23 = cvt_pk_bf16(q2, q3);
    *(uint2v*)(q_hi + base) = uint2v{qh01, qh23};
    float ql0 = q0 - __uint_as_float(qh01 << 16);
    float ql1 = q1 - __uint_as_float(qh01 & 0xFFFF0000u);
    float ql2 = q2 - __uint_as_float(qh23 << 16);
    float ql3 = q3 - __uint_as_float(qh23 & 0xFFFF0000u);
    *(uint2v*)(q_lo + base) = uint2v{cvt_pk_bf16(ql0, ql1), cvt_pk_bf16(ql2, ql3)};

    float k0 = kv[0] * ik, k1 = kv[1] * ik, k2 = kv[2] * ik, k3 = kv[3] * ik;
    unsigned kh01 = cvt_pk_bf16(k0, k1), kh23 = cvt_pk_bf16(k2, k3);
    *(uint2v*)(k_hi + base) = uint2v{kh01, kh23};
    float kl0 = k0 - __uint_as_float(kh01 << 16);
    float kl1 = k1 - __uint_as_float(kh01 & 0xFFFF0000u);
    float kl2 = k2 - __uint_as_float(kh23 << 16);
    float kl3 = k3 - __uint_as_float(kh23 & 0xFFFF0000u);
    *(uint2v*)(k_lo + base) = uint2v{cvt_pk_bf16(kl0, kl1), cvt_pk_bf16(kl2, kl3)};

#pragma unroll
    for (int dd = 0; dd < 4; ++dd) {
      int d = dg * 4 + dd;
      vt[(bh_ * 32 + d) * S_ + s] = f2bf1(vv[dd]);
    }
  }
}

// ---------------- K3: fused QK^T (split-bf16) -> exact top-512 -> softmax -> PV ----------------
// (R15 keeper: 1024 thr, pipelined quarter staging, single-seed Illinois + Newton 2nd pivot,
//  paired-column selection, double half-P buffers)
__global__ __launch_bounds__(1024, 8) void k_attn(const unsigned short* __restrict__ q_hi,
                                                  const unsigned short* __restrict__ q_lo,
                                                  const unsigned short* __restrict__ k_hi,
                                                  const unsigned short* __restrict__ k_lo,
                                                  const unsigned short* __restrict__ vt,
                                                  unsigned short* __restrict__ ao) {
  extern __shared__ float smem[];
  __shared__ float is_arr[QT];
  unsigned short* Pb = (unsigned short*)smem;
  float* red = smem;
  int bid = blockIdx.x;
  int tile = bid & 127;
  int bh = bid >> 7;
  int q0 = tile * QT;
  int tid = threadIdx.x, lane = tid & 63, wv = tid >> 6;
  int l15 = lane & 15, lh = lane >> 4;
  const unsigned short* vb = vt + (size_t)bh * 32 * S_;

  size_t qoff = ((size_t)bh * S_ + q0 + l15) * 32 + lh * 8;
  short8 ah = *(const short8*)(q_hi + qoff);
  short8 al = *(const short8*)(q_lo + qoff);
  size_t kbase = (size_t)bh * S_ * 32;

  float v[32];

  short8 kh0, kl0, kh1, kl1;
  {
    const unsigned short* kp = k_hi + kbase + (size_t)(wv * 32 + l15) * 32 + lh * 8;
    const unsigned short* lp = k_lo + kbase + (size_t)(wv * 32 + l15) * 32 + lh * 8;
    kh0 = *(const short8*)(kp);       kl0 = *(const short8*)(lp);
    kh1 = *(const short8*)(kp + 512); kl1 = *(const short8*)(lp + 512);
  }
#pragma unroll
  for (int qq = 0; qq < 4; ++qq) {
    float* buf = smem + (qq & 1) * QBUF;
    {
      f32x4 d0 = {}, d1 = {};
      __builtin_amdgcn_s_setprio(1);
      d0 = __builtin_amdgcn_mfma_f32_16x16x32_bf16(ah, kh0, d0, 0, 0, 0);
      d0 = __builtin_amdgcn_mfma_f32_16x16x32_bf16(ah, kl0, d0, 0, 0, 0);
      d0 = __builtin_amdgcn_mfma_f32_16x16x32_bf16(al, kh0, d0, 0, 0, 0);
      d1 = __builtin_amdgcn_mfma_f32_16x16x32_bf16(ah, kh1, d1, 0, 0, 0);
      d1 = __builtin_amdgcn_mfma_f32_16x16x32_bf16(ah, kl1, d1, 0, 0, 0);
      d1 = __builtin_amdgcn_mfma_f32_16x16x32_bf16(al, kh1, d1, 0, 0, 0);
      __builtin_amdgcn_s_setprio(0);
      int tloc = wv * 32 + l15;
#pragma unroll
      for (int r = 0; r < 4; ++r) {
        buf[(lh * 4 + r) * QSTR + tloc] = d0[r];
        buf[(lh * 4 + r) * QSTR + tloc + 16] = d1[r];
      }
      if (qq < 3) {
        int colg = (qq + 1) * QCOLS + wv * 32;
        const unsigned short* kp = k_hi + kbase + (size_t)(colg + l15) * 32 + lh * 8;
        const unsigned short* lp = k_lo + kbase + (size_t)(colg + l15) * 32 + lh * 8;
        kh0 = *(const short8*)(kp);       kl0 = *(const short8*)(lp);
        kh1 = *(const short8*)(kp + 512); kl1 = *(const short8*)(lp + 512);
      }
    }
    __syncthreads();
#pragma unroll
    for (int kk2 = 0; kk2 < 4; ++kk2) {
      f32x2 pr = *(const f32x2*)&buf[wv * QSTR + kk2 * 128 + 2 * lane];
      v[qq * 8 + kk2 * 2] = pr[0];
      v[qq * 8 + kk2 * 2 + 1] = pr[1];
    }
  }

  {
    float vmax = v[0], vmin = v[0], sum = 0.f, sqs = 0.f;
#pragma unroll
    for (int j = 0; j < 32; ++j) {
      vmax = fmaxf(vmax, v[j]); vmin = fminf(vmin, v[j]);
      sum += v[j]; sqs = fmaf(v[j], v[j], sqs);
    }
#pragma unroll
    for (int m = 1; m < 64; m <<= 1) {
      vmax = fmaxf(vmax, __shfl_xor(vmax, m));
      vmin = fminf(vmin, __shfl_xor(vmin, m));
      sum += __shfl_xor(sum, m);
      sqs += __shfl_xor(sqs, m);
    }
    float mu = sum * (1.f / 2048.f);
    float sig = sqrtf(fmaxf(sqs * (1.f / 2048.f) - mu * mu, 0.f));

    float vlo = vmin - 1e-3f, vhi = vmax;
    float flo = 1536.f, fhi = -512.f;
    int chi = 0;
    float T = vhi;
    bool exact = false;
    int lastside = 0;
    float piv = mu + 0.67449f * sig;
    if (!(piv > vlo && piv < vhi)) piv = 0.5f * (vlo + vhi);
    for (int it = 0; it < 32; ++it) {
      int c = 0;
#pragma unroll
      for (int j = 0; j < 32; ++j)
        c += (int)__popcll(__ballot(v[j] > piv));
      if (c == TOPK) { T = piv; exact = true; break; }
      if (c > TOPK) {
        if (lastside == 1) fhi *= 0.5f;
        vlo = piv; flo = (float)(c - TOPK); lastside = 1;
      } else {
        if (lastside == -1) flo *= 0.5f;
        vhi = piv; fhi = (float)(c - TOPK); chi = c; lastside = -1;
      }
      float npiv;
      if (it == 0 && sig > 1e-20f) {
        float z = (piv - mu) / sig;
        float dens = 0.398942f * __expf(-0.5f * z * z) * (2048.f / sig);
        npiv = piv + (float)(c - TOPK) / fmaxf(dens, 1e-6f);
      } else {
        npiv = vhi - fhi * (vhi - vlo) / (fhi - flo);
      }
      if (!(npiv > vlo && npiv < vhi)) npiv = 0.5f * (vlo + vhi);
      if (!(npiv > vlo && npiv < vhi)) break;
      piv = npiv;
    }
    int cntGT = exact ? TOPK : chi;
    if (!exact) T = vhi;

    unsigned selbits = 0;
#pragma unroll
    for (int j = 0; j < 32; ++j)
      if (v[j] > T) selbits |= (1u << j);
    int need = TOPK - cntGT;
    if (need > 0) {
      int base = 0;
      unsigned long long lmask = (lane == 0) ? 0ull : (~0ull >> (64 - lane));
#pragma unroll
      for (int k = 0; k < 16; ++k) {
        bool t0 = (v[2 * k] == T), t1 = (v[2 * k + 1] == T);
        unsigned long long m0 = __ballot(t0);
        unsigned long long m1 = __ballot(t1);
        int before = base + (int)__popcll(m0 & lmask) + (int)__popcll(m1 & lmask);
        int r0 = before;
        int r1 = before + (t0 ? 1 : 0);
        if (t0 && r0 < need) selbits |= (1u << (2 * k));
        if (t1 && r1 < need) selbits |= (1u << (2 * k + 1));
        base += (int)__popcll(m0) + (int)__popcll(m1);
      }
    }

    float ssum = 0.f;
#pragma unroll
    for (int j = 0; j < 32; ++j) {
      float e = ((selbits >> j) & 1u) ? __expf(v[j] - vmax) : 0.f;
      v[j] = e;
      ssum += e;
    }
#pragma unroll
    for (int m = 1; m < 64; m <<= 1) ssum += __shfl_xor(ssum, m);
    if (lane == 0) is_arr[wv] = 1.f / ssum;
  }

  f32x4 acc0 = {}, acc1 = {};
  int swz_w = (wv & 7) << 3;
  int swz_r = (l15 & 7) << 3;
#pragma unroll
  for (int kk = 0; kk < 8; ++kk) {
    int lc = (kk >> 2) * 512 + (kk & 3) * 128 + 2 * lane;
    unsigned pk = cvt_pk_bf16(v[2 * kk], v[2 * kk + 1]);
    *(unsigned*)&Pb[(wv * PSTH + lc) ^ swz_w] = pk;
  }
  __syncthreads();
  {
#pragma unroll
    for (int kk = 0; kk < 8; ++kk) {
      int lc = (kk >> 2) * 512 + (kk & 3) * 128 + 2 * lane;
      unsigned pk = cvt_pk_bf16(v[16 + 2 * kk], v[16 + 2 * kk + 1]);
      *(unsigned*)&Pb[P1OFF + ((wv * PSTH + lc) ^ swz_w)] = pk;
    }
    const unsigned short* v0p = vb + (size_t)l15 * S_ + wv * 64 + lh * 8;
    const unsigned short* v1p = v0p + 16 * S_;
#pragma unroll
    for (int kt = 0; kt < 2; ++kt) {
      int lc = wv * 64 + kt * 32 + lh * 8;
      short8 a = *(const short8*)(Pb + ((l15 * PSTH + lc) ^ swz_r));
      short8 b0 = *(const short8*)(v0p + kt * 32);
      short8 b1 = *(const short8*)(v1p + kt * 32);
      __builtin_amdgcn_s_setprio(1);
      acc0 = __builtin_amdgcn_mfma_f32_16x16x32_bf16(a, b0, acc0, 0, 0, 0);
      acc1 = __builtin_amdgcn_mfma_f32_16x16x32_bf16(a, b1, acc1, 0, 0, 0);
      __builtin_amdgcn_s_setprio(0);
    }
  }
  __syncthreads();
  {
    const unsigned short* v0p = vb + (size_t)l15 * S_ + 1024 + wv * 64 + lh * 8;
    const unsigned short* v1p = v0p + 16 * S_;
#pragma unroll
    for (int kt = 0; kt < 2; ++kt) {
      int lc = wv * 64 + kt * 32 + lh * 8;
      short8 a = *(const short8*)(Pb + P1OFF + ((l15 * PSTH + lc) ^ swz_r));
      short8 b0 = *(const short8*)(v0p + kt * 32);
      short8 b1 = *(const short8*)(v1p + kt * 32);
      __builtin_amdgcn_s_setprio(1);
      acc0 = __builtin_amdgcn_mfma_f32_16x16x32_bf16(a, b0, acc0, 0, 0, 0);
      acc1 = __builtin_amdgcn_mfma_f32_16x16x32_bf16(a, b1, acc1, 0, 0, 0);
      __builtin_amdgcn_s_setprio(0);
    }
  }
  __syncthreads();

#pragma unroll
  for (int r = 0; r < 4; ++r) {
    red[wv * 529 + (lh * 4 + r) * 33 + l15] = acc0[r];
    red[wv * 529 + (lh * 4 + r) * 33 + 16 + l15] = acc1[r];
  }
  __syncthreads();
  if (tid < 512) {
    int row = tid >> 5, d = tid & 31;
    float s = 0.f;
#pragma unroll
    for (int w = 0; w < 16; ++w) s += red[w * 529 + row * 33 + d];
    s *= is_arr[row];
    ao[((size_t)bh * S_ + q0 + row) * 32 + d] = f2bf1(s);
  }
}

// ---------------- K4: output projection ----------------
__global__ __launch_bounds__(256) void k_proj(const unsigned short* __restrict__ wbf,
                                              const unsigned short* __restrict__ ao,
                                              float* __restrict__ out) {
  int b = blockIdx.z;
  int m0 = blockIdx.y * 64, n0 = blockIdx.x * 64;
  int tid = threadIdx.x, lane = tid & 63, wid = tid >> 6;
  int l15 = lane & 15, lh = lane >> 4;
  int wm = (wid >> 1) * 32, wn = (wid & 1) * 32;
  const unsigned short* aob = ao + (size_t)b * H_ * S_ * 32;
  f32x4 acc[2][2] = {};
  int mA = m0 + wm + l15;
  int nB = n0 + wn + l15;
  for (int k0 = 0; k0 < C_; k0 += 32) {
    int kk = k0 + lh * 8;
    int hh = kk >> 5;
    int dd = kk & 31;
    short8 a0 = *(const short8*)(wbf + (size_t)mA * C_ + kk);
    short8 a1 = *(const short8*)(wbf + (size_t)(mA + 16) * C_ + kk);
    short8 b0 = *(const short8*)(aob + ((size_t)hh * S_ + nB) * 32 + dd);
    short8 b1 = *(const short8*)(aob + ((size_t)hh * S_ + nB + 16) * 32 + dd);
    acc[0][0] = __builtin_amdgcn_mfma_f32_16x16x32_bf16(a0, b0, acc[0][0], 0, 0, 0);
    acc[0][1] = __builtin_amdgcn_mfma_f32_16x16x32_bf16(a0, b1, acc[0][1], 0, 0, 0);
    acc[1][0] = __builtin_amdgcn_mfma_f32_16x16x32_bf16(a1, b0, acc[1][0], 0, 0, 0);
    acc[1][1] = __builtin_amdgcn_mfma_f32_16x16x32_bf16(a1, b1, acc[1][1], 0, 0, 0);
  }
  float* ob = out + (size_t)b * C_ * S_;
#pragma unroll
  for (int i = 0; i < 2; ++i)
#pragma unroll
    for (int j = 0; j < 2; ++j)
#pragma unroll
      for (int r = 0; r < 4; ++r) {
        int row = m0 + wm + i * 16 + lh * 4 + r;
        int col = n0 + wn + j * 16 + l15;
        ob[(size_t)row * S_ + col] = acc[i][j][r];
      }
}

extern "C" void kernel_launch(void* const* d_in, const int* in_sizes, int n_in,
                              void* d_out, int out_size, void* d_ws, size_t ws_size,
                              hipStream_t stream) {
  const float* x = (const float*)d_in[0];
  const float* wqkv = (const float*)d_in[1];
  const float* wdw = (const float*)d_in[2];
  const float* wproj = (const float*)d_in[3];
  const float* temp = (const float*)d_in[4];
  float* out = (float*)d_out;

  char* ws = (char*)d_ws;
  size_t off = 0;
  auto alloc = [&](size_t bytes) -> void* {
    void* p = ws + off;
    off += (bytes + 255) & ~(size_t)255;
    return p;
  };
  unsigned short* wq_hi    = (unsigned short*)alloc((size_t)O3_ * C_ * 2);
  unsigned short* wq_lo    = (unsigned short*)alloc((size_t)O3_ * C_ * 2);
  unsigned short* wproj_bf = (unsigned short*)alloc((size_t)C_ * C_ * 2);
  unsigned short* q_hi     = (unsigned short*)alloc((size_t)B_ * H_ * S_ * 32 * 2);
  unsigned short* q_lo     = (unsigned short*)alloc((size_t)B_ * H_ * S_ * 32 * 2);
  unsigned short* k_hi     = (unsigned short*)alloc((size_t)B_ * H_ * S_ * 32 * 2);
  unsigned short* k_lo     = (unsigned short*)alloc((size_t)B_ * H_ * S_ * 32 * 2);
  unsigned short* vt       = (unsigned short*)alloc((size_t)B_ * H_ * 32 * S_ * 2);
  unsigned short* ao       = (unsigned short*)alloc((size_t)B_ * H_ * S_ * 32 * 2);

  (void)hipFuncSetAttribute(reinterpret_cast<const void*>(k_attn),
                            hipFuncAttributeMaxDynamicSharedMemorySize, (int)K3_LDS_BYTES);

  k_convw<<<dim3((O3_ * C_ + 255) / 256), dim3(256), 0, stream>>>(wqkv, wproj, wq_hi, wq_lo, wproj_bf);
  k_qkvf<<<dim3(S_ / 64, H_, B_), dim3(512), 0, stream>>>(wq_hi, wq_lo, x, wdw, temp,
                                                          q_hi, q_lo, k_hi, k_lo, vt);
  k_attn<<<dim3(B_ * H_ * (S_ / QT)), dim3(1024), K3_LDS_BYTES, stream>>>(q_hi, q_lo, k_hi, k_lo, vt, ao);
  k_proj<<<dim3(S_ / 64, C_ / 64, B_), dim3(256), 0, stream>>>(wproj_bf, ao, out);
}